// Round 9
// baseline (122.872 us; speedup 1.0000x reference)
//
#include <hip/hip_runtime.h>

#define N_NODES 10000
#define N_EDGES 640000
#define D 128
#define NQ (N_EDGES / 4)      // 160000 edge quads

#define NCHUNK 64             // scatter chunks (= scatter blocks)
#define QPC (NQ / NCHUNK)     // 2500 quads (10000 edges) per chunk, exact
#define GEMM_BLOCKS 157       // 64 nodes per block (MFMA)
#define GRID1 (NCHUNK + GEMM_BLOCKS)   // 221
#define RCAP 8                // per (row,chunk) cell cap: mean 1.0, P(>8)~1e-6
#define SPILLCAP 10000        // worst case: a chunk spills every edge
#define CAP2 128              // per-row queue cap (mean 64, +8 sigma; slow path)
#define QPAD2 144             // CAP2 + 16 zero-pad
#define LSTR 136              // LDS row stride in ushorts (272B)

typedef unsigned int uint32;
typedef unsigned long long u64;
typedef unsigned short u16;
typedef unsigned char u8;
using short8 = __attribute__((ext_vector_type(8))) short;
using f32x4  = __attribute__((ext_vector_type(4))) float;

__device__ __forceinline__ uint32 f2bf_bits(float f) {
    uint32 u = __float_as_uint(f);
    return (u + 0x7FFFu + ((u >> 16) & 1u)) >> 16;   // RNE bf16 bits
}
__device__ __forceinline__ uint32 pack2(float lo, float hi) {
    return f2bf_bits(lo) | (f2bf_bits(hi) << 16);
}

// R17: MEASUREMENT ROUND. R13-R16 were four consecutive nulls on k2 theories;
// k2's duration has never been directly observed since it dropped below the
// 43us poison fill. Both kernels are idempotent, so spmm is launched TWICE
// (scratch target, then real): dur_R17 - dur_R16 ~= k2 + ~4us boundary.
// Pre-committed: delta ~35 => k2~30 real, attack gather data path next;
// delta ~12 => k2 small, attack k1/floor next. Kernels byte-identical to R16.
__global__ __launch_bounds__(256, 4) void gemm_scatter_kernel(
    const float* __restrict__ x, const float* __restrict__ w,
    const int* __restrict__ row, const int* __restrict__ col,
    const float* __restrict__ val,
    uint32* __restrict__ h2, u8* __restrict__ cnts2,
    int* __restrict__ spillcnt, uint32* __restrict__ bstore,
    uint2* __restrict__ spill)
{
    __shared__ __align__(16) int SH[N_NODES];      // 40000 B (hist / Ws alias)
    __shared__ int spillc;
    const int t = threadIdx.x;

    if (blockIdx.x < NCHUNK) {
        // ---- chunk scatter: single pass, per-row LDS histogram ----
        int* hist = SH;
        for (int i = t; i < N_NODES; i += 256) hist[i] = 0;
        if (t == 0) spillc = 0;
        __syncthreads();

        const int sb = blockIdx.x;
        const int4*   row4 = (const int4*)row;
        const int4*   col4 = (const int4*)col;
        const float4* val4 = (const float4*)val;
        const int i0 = sb * QPC;
        for (int i = i0 + t; i < i0 + QPC; i += 256) {
            int4 r = row4[i]; int4 c = col4[i]; float4 v = val4[i];
            #pragma unroll
            for (int e = 0; e < 4; ++e) {
                int rr = (e == 0) ? r.x : (e == 1) ? r.y : (e == 2) ? r.z : r.w;
                int cc = (e == 0) ? c.x : (e == 1) ? c.y : (e == 2) ? c.z : c.w;
                float vv = (e == 0) ? v.x : (e == 1) ? v.y : (e == 2) ? v.z : v.w;
                uint32 rc = (uint32)cc | (f2bf_bits(vv) << 16);
                int k = atomicAdd(&hist[rr], 1);           // LDS, ~no contention
                if (k < RCAP)
                    bstore[(size_t)rr * (NCHUNK * RCAP) + sb * RCAP + k] = rc;
                else {                                     // P ~ 1e-6, ~never
                    int ks = atomicAdd(&spillc, 1);
                    spill[(size_t)sb * SPILLCAP + ks] = make_uint2(rc, (uint32)rr);
                }
            }
        }
        __syncthreads();
        for (int r = t; r < N_NODES; r += 256) {           // coalesced u8 writes
            int c = hist[r];
            cnts2[(size_t)sb * N_NODES + r] = (u8)((c < RCAP) ? c : RCAP);
        }
        if (t == 0) spillcnt[sb] = spillc;                 // unconditional
    } else {
        // ---- MFMA GEMM: 64 rows/block, 4 waves x 16 rows x 128 cols.
        // A direct global->reg; W staged col-major in LDS (float4 loads).
        // C/D: col=lane&15, row=quad*4+reg (HW-verified).
        u16* Ws = (u16*)SH;
        const int g = blockIdx.x - NCHUNK;
        const int lane = t & 63;
        const int wid  = t >> 6;
        const int q = lane >> 4, cl = lane & 15;

        const float4* w4 = (const float4*)w;
        #pragma unroll
        for (int i = 0; i < 8; ++i) {                 // stage W^T (128x128)
            int lin = t + i * 256;                    // m(k-pair) x qc(col-quad)
            int m  = lin >> 5;
            int qc = lin & 31;
            float4 r0 = w4[(2 * m) * 32 + qc];        // row 2m, cols 4qc..4qc+3
            float4 r1 = w4[(2 * m + 1) * 32 + qc];
            int c = qc * 4;
            *(uint32*)&Ws[(c + 0) * LSTR + 2 * m] = pack2(r0.x, r1.x);
            *(uint32*)&Ws[(c + 1) * LSTR + 2 * m] = pack2(r0.y, r1.y);
            *(uint32*)&Ws[(c + 2) * LSTR + 2 * m] = pack2(r0.z, r1.z);
            *(uint32*)&Ws[(c + 3) * LSTR + 2 * m] = pack2(r0.w, r1.w);
        }

        int gr = g * 64 + wid * 16 + cl;              // A-fragment row
        if (gr >= N_NODES) gr = N_NODES - 1;          // tail clamp (guarded write)
        const float* xrow = &x[(size_t)gr * D];
        float4 xv[8];
        #pragma unroll
        for (int kk = 0; kk < 4; ++kk) {
            xv[2 * kk]     = *(const float4*)&xrow[kk * 32 + q * 8];
            xv[2 * kk + 1] = *(const float4*)&xrow[kk * 32 + q * 8 + 4];
        }
        __syncthreads();

        f32x4 acc[8] = {};
        #pragma unroll
        for (int kk = 0; kk < 4; ++kk) {
            union { short8 s; uint32 u[4]; } af;
            float4 a = xv[2 * kk], b = xv[2 * kk + 1];
            af.u[0] = pack2(a.x, a.y); af.u[1] = pack2(a.z, a.w);
            af.u[2] = pack2(b.x, b.y); af.u[3] = pack2(b.z, b.w);
            #pragma unroll
            for (int ct = 0; ct < 8; ++ct) {
                short8 bf = *(const short8*)&Ws[(ct * 16 + cl) * LSTR + kk * 32 + q * 8];
                acc[ct] = __builtin_amdgcn_mfma_f32_16x16x32_bf16(af.s, bf, acc[ct], 0, 0, 0);
            }
        }
        #pragma unroll
        for (int reg = 0; reg < 4; ++reg) {
            int node = g * 64 + wid * 16 + q * 4 + reg;
            if (node < N_NODES) {
                uint32* base = h2 + (size_t)node * 64 + cl;
                #pragma unroll
                for (int ct = 0; ct < 4; ++ct)
                    base[ct * 16] = pack2(acc[ct][reg], acc[ct + 4][reg]);
            }
        }
    }
}

// k2: byte-identical to R16 (per-block LDS count-transpose, shfl prefix
// compaction, gated cell loads, proven depth-8 pipelined gather).
__global__ __launch_bounds__(256) void spmm_kernel(
    const uint32* __restrict__ bstore, const u8* __restrict__ cnts2,
    const int* __restrict__ spillcnt, const uint2* __restrict__ spill,
    const uint32* __restrict__ h2, const float* __restrict__ bias,
    float* __restrict__ out)
{
    __shared__ uint32 qbuf[8 * QPAD2];    // per-(wave,half) queues (4608 B)
    __shared__ u64 lcnt8[NCHUNK];         // transposed counts (512 B)
    const int t = threadIdx.x;
    const int lane = t & 63;
    const int wid  = t >> 6;
    const int r0 = blockIdx.x * 8;

    if (t < NCHUNK)
        lcnt8[t] = *(const u64*)&cnts2[(size_t)t * N_NODES + r0];  // aligned
    const bool anyspill = __ballot(spillcnt[lane] != 0) != 0ull;
    __syncthreads();

    for (int half = 0; half < 2; ++half) {
        const int d = wid * 2 + half;
        const int r = r0 + d;
        uint32* qp = &qbuf[d * QPAD2];

        // ---- prefix-compaction queue build (atomic-free, compare-free) ----
        int c = (int)((lcnt8[lane] >> (8 * d)) & 0xFFu);  // lane = chunk
        int p = c;
        #pragma unroll
        for (int s = 1; s < 64; s <<= 1) {
            int v = __shfl_up(p, s);
            if (lane >= s) p += v;
        }
        int ntot = __shfl(p, 63);
        int base = p - c;
        const uint32* cell = &bstore[(size_t)r * (NCHUNK * RCAP) + lane * RCAP];
        uint4 c0 = {0, 0, 0, 0}, c1 = {0, 0, 0, 0};
        if (c > 0) c0 = *(const uint4*)cell;              // 16B (strip contig)
        if (c > 4) c1 = *(const uint4*)(cell + 4);        // P(c>4) ~ 0.4%
        if (c > 0 && base + 0 < CAP2) qp[base + 0] = c0.x;
        if (c > 1 && base + 1 < CAP2) qp[base + 1] = c0.y;
        if (c > 2 && base + 2 < CAP2) qp[base + 2] = c0.z;
        if (c > 3 && base + 3 < CAP2) qp[base + 3] = c0.w;
        if (c > 4 && base + 4 < CAP2) qp[base + 4] = c1.x;
        if (c > 5 && base + 5 < CAP2) qp[base + 5] = c1.y;
        if (c > 6 && base + 6 < CAP2) qp[base + 6] = c1.z;
        if (c > 7 && base + 7 < CAP2) qp[base + 7] = c1.w;

        if (anyspill) {                                   // ~never taken
            for (int ch = 0; ch < NCHUNK; ++ch) {
                int sc = spillcnt[ch];
                for (int k = 0; k < sc; ++k) {
                    uint2 e = spill[(size_t)ch * SPILLCAP + k];
                    if (e.y == (uint32)r) {
                        if (lane == 0 && ntot < CAP2) qp[ntot] = e.x;
                        ntot++;
                    }
                }
            }
        }

        float a0 = 0.f, a1 = 0.f;
        if (ntot <= CAP2) {
            if (lane < 16) qp[ntot + lane] = 0;    // zero pad (val=+0.0 recs)
            __builtin_amdgcn_s_waitcnt(0);         // wave-local LDS drain

            const int npad = (ntot + 7) & ~7;
            uint32 rq0,rq1,rq2,rq3,rq4,rq5,rq6,rq7;
            uint32 hh0,hh1,hh2,hh3,hh4,hh5,hh6,hh7;
            rq0 = qp[0]; hh0 = h2[((rq0 & 0xFFFFu) << 6) + lane];
            rq1 = qp[1]; hh1 = h2[((rq1 & 0xFFFFu) << 6) + lane];
            rq2 = qp[2]; hh2 = h2[((rq2 & 0xFFFFu) << 6) + lane];
            rq3 = qp[3]; hh3 = h2[((rq3 & 0xFFFFu) << 6) + lane];
            rq4 = qp[4]; hh4 = h2[((rq4 & 0xFFFFu) << 6) + lane];
            rq5 = qp[5]; hh5 = h2[((rq5 & 0xFFFFu) << 6) + lane];
            rq6 = qp[6]; hh6 = h2[((rq6 & 0xFFFFu) << 6) + lane];
            rq7 = qp[7]; hh7 = h2[((rq7 & 0xFFFFu) << 6) + lane];

#define CONSUME_PREFETCH(RQ, HH, P)                                          \
    {                                                                        \
        a0 = fmaf(__uint_as_float(RQ & 0xFFFF0000u),                         \
                  __uint_as_float(HH << 16), a0);                            \
        a1 = fmaf(__uint_as_float(RQ & 0xFFFF0000u),                         \
                  __uint_as_float(HH & 0xFFFF0000u), a1);                    \
        uint32 rn = qp[j + 8 + P];                                           \
        RQ = rn; HH = h2[((rn & 0xFFFFu) << 6) + lane];                      \
    }

            for (int j = 0; j < npad; j += 8) {
                CONSUME_PREFETCH(rq0, hh0, 0)
                CONSUME_PREFETCH(rq1, hh1, 1)
                CONSUME_PREFETCH(rq2, hh2, 2)
                CONSUME_PREFETCH(rq3, hh3, 3)
                CONSUME_PREFETCH(rq4, hh4, 4)
                CONSUME_PREFETCH(rq5, hh5, 5)
                CONSUME_PREFETCH(rq6, hh6, 6)
                CONSUME_PREFETCH(rq7, hh7, 7)
            }
#undef CONSUME_PREFETCH
        } else {
            // slow path (row > CAP2 records; ~never): rescan row cells + spills.
            for (int ch = 0; ch < NCHUNK; ++ch) {
                int c2 = (int)((lcnt8[ch] >> (8 * d)) & 0xFFu);
                for (int k = 0; k < c2; ++k) {
                    uint32 rec = bstore[(size_t)r * (NCHUNK * RCAP) + ch * RCAP + k];
                    uint32 hv = h2[((rec & 0xFFFFu) << 6) + lane];
                    a0 = fmaf(__uint_as_float(rec & 0xFFFF0000u),
                              __uint_as_float(hv << 16), a0);
                    a1 = fmaf(__uint_as_float(rec & 0xFFFF0000u),
                              __uint_as_float(hv & 0xFFFF0000u), a1);
                }
            }
            for (int ch = 0; ch < NCHUNK; ++ch) {
                int sc = spillcnt[ch];
                for (int k = 0; k < sc; ++k) {
                    uint2 e = spill[(size_t)ch * SPILLCAP + k];
                    if (e.y == (uint32)r) {
                        uint32 hv = h2[((e.x & 0xFFFFu) << 6) + lane];
                        a0 = fmaf(__uint_as_float(e.x & 0xFFFF0000u),
                                  __uint_as_float(hv << 16), a0);
                        a1 = fmaf(__uint_as_float(e.x & 0xFFFF0000u),
                                  __uint_as_float(hv & 0xFFFF0000u), a1);
                    }
                }
            }
        }

        out[(size_t)r * D + lane]      = a0 + bias[lane];
        out[(size_t)r * D + 64 + lane] = a1 + bias[lane + 64];
    }
}

extern "C" void kernel_launch(void* const* d_in, const int* in_sizes, int n_in,
                              void* d_out, int out_size, void* d_ws, size_t ws_size,
                              hipStream_t stream)
{
    const float* x    = (const float*)d_in[0];
    const float* aval = (const float*)d_in[1];
    const float* w    = (const float*)d_in[2];
    const float* bias = (const float*)d_in[3];
    const int* arow   = (const int*)d_in[4];
    const int* acol   = (const int*)d_in[5];

    char* ws = (char*)d_ws;
    uint32* h2       = (uint32*)(ws);              //  2,560,000 B
    u8*     cnts2    = (u8*)(ws + 2560000);        //    640,000 B (64 x 10000)
    int*    spillcnt = (int*)(ws + 3200000);       //        256 B (64) +pad
    uint32* bstore   = (uint32*)(ws + 3200512);    // 20,480,000 B (10000x64x8x4)
    uint2*  spill    = (uint2*)(ws + 23680512);    //  5,120,000 B (64x10000x8)
    float*  oscratch = (float*)(ws + 28800512);    //  5,120,000 B (k2-probe out)
    // total 33,920,512 B; no memset needed.

    gemm_scatter_kernel<<<GRID1, 256, 0, stream>>>(
        x, w, arow, acol, aval, h2, cnts2, spillcnt, bstore, spill);
    // probe launch (scratch target) -- dur delta vs R16 measures k2 directly
    spmm_kernel<<<N_NODES / 8, 256, 0, stream>>>(
        bstore, cnts2, spillcnt, spill, h2, bias, oscratch);
    spmm_kernel<<<N_NODES / 8, 256, 0, stream>>>(
        bstore, cnts2, spillcnt, spill, h2, bias, (float*)d_out);
}

// Round 10
// 104.675 us; speedup vs baseline: 1.1738x; 1.1738x over previous
//
#include <hip/hip_runtime.h>

#define N_NODES 10000
#define N_EDGES 640000
#define D 128
#define NQ (N_EDGES / 4)      // 160000 edge quads

#define NCHUNK 256            // scatter chunks (= dedicated scatter blocks)
#define QPC (NQ / NCHUNK)     // 625 quads (2500 edges) per chunk, exact
#define GEMM_BLOCKS 157       // 64 nodes per block (MFMA)
#define GRID1 (NCHUNK + GEMM_BLOCKS)   // 413 blocks, all co-resident
#define RCAP 8                // per (row,chunk) cell cap: mean 0.25, P(>8)~0
#define SPILLCAP 2500         // worst case: a chunk spills every edge
#define CAP2 128              // per-row queue cap (mean 64, +8 sigma; slow path)
#define QPAD2 144             // CAP2 + 16 zero-pad
#define LSTR 136              // LDS row stride in ushorts (272B)

typedef unsigned int uint32;
typedef unsigned long long u64;
typedef unsigned short u16;
typedef unsigned char u8;
using short8 = __attribute__((ext_vector_type(8))) short;
using f32x4  = __attribute__((ext_vector_type(4))) float;

__device__ __forceinline__ uint32 f2bf_bits(float f) {
    uint32 u = __float_as_uint(f);
    return (u + 0x7FFFu + ((u >> 16) & 1u)) >> 16;   // RNE bf16 bits
}
__device__ __forceinline__ uint32 pack2(float lo, float hi) {
    return f2bf_bits(lo) | (f2bf_bits(hi) << 16);
}

// R18: R17 MEASURED k2 ~= 12us => k1 ~= 44us is the pig. Cause: R15 cut
// scatter to 64 blocks (to fit the 40KB per-row histogram) -- only 64 CUs
// scatter, ~39 scattered line-RMWs per thread, latency/concurrency-bound.
// (Cross-check: R12's 256-scatter-block k1 ~= 19us.) Fix: 256 dedicated
// scatter blocks (2500 edges each) + 157 GEMM blocks, 413 total, all
// co-resident (40KB LDS => 2+ blocks/CU). bstore = [row][256][8] = 82MB --
// the 256MiB poison fill proves ws_size ~= 256MB, so this is safe. k2: each
// lane owns 4 chunks in the prefix-compaction; gather engine unchanged.
__global__ __launch_bounds__(256, 4) void gemm_scatter_kernel(
    const float* __restrict__ x, const float* __restrict__ w,
    const int* __restrict__ row, const int* __restrict__ col,
    const float* __restrict__ val,
    uint32* __restrict__ h2, u8* __restrict__ cnts2,
    int* __restrict__ spillcnt, uint32* __restrict__ bstore,
    uint2* __restrict__ spill)
{
    __shared__ __align__(16) int SH[N_NODES];      // 40000 B (hist / Ws alias)
    __shared__ int spillc;
    const int t = threadIdx.x;

    if (blockIdx.x < NCHUNK) {
        // ---- chunk scatter: single pass, per-row LDS histogram ----
        int* hist = SH;
        for (int i = t; i < N_NODES; i += 256) hist[i] = 0;
        if (t == 0) spillc = 0;
        __syncthreads();

        const int sb = blockIdx.x;
        const int4*   row4 = (const int4*)row;
        const int4*   col4 = (const int4*)col;
        const float4* val4 = (const float4*)val;
        const int i0 = sb * QPC;
        for (int i = i0 + t; i < i0 + QPC; i += 256) {
            int4 r = row4[i]; int4 c = col4[i]; float4 v = val4[i];
            #pragma unroll
            for (int e = 0; e < 4; ++e) {
                int rr = (e == 0) ? r.x : (e == 1) ? r.y : (e == 2) ? r.z : r.w;
                int cc = (e == 0) ? c.x : (e == 1) ? c.y : (e == 2) ? c.z : c.w;
                float vv = (e == 0) ? v.x : (e == 1) ? v.y : (e == 2) ? v.z : v.w;
                uint32 rc = (uint32)cc | (f2bf_bits(vv) << 16);
                int k = atomicAdd(&hist[rr], 1);           // LDS, ~no contention
                if (k < RCAP)
                    bstore[(size_t)rr * (NCHUNK * RCAP) + sb * RCAP + k] = rc;
                else {                                     // P ~ 0, ~never
                    int ks = atomicAdd(&spillc, 1);
                    spill[(size_t)sb * SPILLCAP + ks] = make_uint2(rc, (uint32)rr);
                }
            }
        }
        __syncthreads();
        for (int r = t; r < N_NODES; r += 256) {           // coalesced u8 writes
            int c = hist[r];
            cnts2[(size_t)sb * N_NODES + r] = (u8)((c < RCAP) ? c : RCAP);
        }
        if (t == 0) spillcnt[sb] = spillc;                 // unconditional
    } else {
        // ---- MFMA GEMM: 64 rows/block, 4 waves x 16 rows x 128 cols.
        // A direct global->reg; W staged col-major in LDS (float4 loads).
        // C/D: col=lane&15, row=quad*4+reg (HW-verified).
        u16* Ws = (u16*)SH;
        const int g = blockIdx.x - NCHUNK;
        const int lane = t & 63;
        const int wid  = t >> 6;
        const int q = lane >> 4, cl = lane & 15;

        const float4* w4 = (const float4*)w;
        #pragma unroll
        for (int i = 0; i < 8; ++i) {                 // stage W^T (128x128)
            int lin = t + i * 256;                    // m(k-pair) x qc(col-quad)
            int m  = lin >> 5;
            int qc = lin & 31;
            float4 r0 = w4[(2 * m) * 32 + qc];        // row 2m, cols 4qc..4qc+3
            float4 r1 = w4[(2 * m + 1) * 32 + qc];
            int c = qc * 4;
            *(uint32*)&Ws[(c + 0) * LSTR + 2 * m] = pack2(r0.x, r1.x);
            *(uint32*)&Ws[(c + 1) * LSTR + 2 * m] = pack2(r0.y, r1.y);
            *(uint32*)&Ws[(c + 2) * LSTR + 2 * m] = pack2(r0.z, r1.z);
            *(uint32*)&Ws[(c + 3) * LSTR + 2 * m] = pack2(r0.w, r1.w);
        }

        int gr = g * 64 + wid * 16 + cl;              // A-fragment row
        if (gr >= N_NODES) gr = N_NODES - 1;          // tail clamp (guarded write)
        const float* xrow = &x[(size_t)gr * D];
        float4 xv[8];
        #pragma unroll
        for (int kk = 0; kk < 4; ++kk) {
            xv[2 * kk]     = *(const float4*)&xrow[kk * 32 + q * 8];
            xv[2 * kk + 1] = *(const float4*)&xrow[kk * 32 + q * 8 + 4];
        }
        __syncthreads();

        f32x4 acc[8] = {};
        #pragma unroll
        for (int kk = 0; kk < 4; ++kk) {
            union { short8 s; uint32 u[4]; } af;
            float4 a = xv[2 * kk], b = xv[2 * kk + 1];
            af.u[0] = pack2(a.x, a.y); af.u[1] = pack2(a.z, a.w);
            af.u[2] = pack2(b.x, b.y); af.u[3] = pack2(b.z, b.w);
            #pragma unroll
            for (int ct = 0; ct < 8; ++ct) {
                short8 bf = *(const short8*)&Ws[(ct * 16 + cl) * LSTR + kk * 32 + q * 8];
                acc[ct] = __builtin_amdgcn_mfma_f32_16x16x32_bf16(af.s, bf, acc[ct], 0, 0, 0);
            }
        }
        #pragma unroll
        for (int reg = 0; reg < 4; ++reg) {
            int node = g * 64 + wid * 16 + q * 4 + reg;
            if (node < N_NODES) {
                uint32* base = h2 + (size_t)node * 64 + cl;
                #pragma unroll
                for (int ct = 0; ct < 4; ++ct)
                    base[ct * 16] = pack2(acc[ct][reg], acc[ct + 4][reg]);
            }
        }
    }
}

// k2: 8 rows/block (1250 blocks). Count-transpose: all 256 threads load one
// u64 (8 rows' counts for one chunk). Queue build: lane owns 4 chunks --
// 4 counts from LDS, 6-step shfl prefix over lane sums, gated 16B cell
// loads, predicated LDS queue writes. Gather: proven branch-free depth-8
// software-pipelined loop (8 L2 gathers in flight).
__global__ __launch_bounds__(256) void spmm_kernel(
    const uint32* __restrict__ bstore, const u8* __restrict__ cnts2,
    const int* __restrict__ spillcnt, const uint2* __restrict__ spill,
    const uint32* __restrict__ h2, const float* __restrict__ bias,
    float* __restrict__ out)
{
    __shared__ uint32 qbuf[8 * QPAD2];    // per-(wave,half) queues (4608 B)
    __shared__ u64 lcnt8[NCHUNK];         // transposed counts (2 KB)
    const int t = threadIdx.x;
    const int lane = t & 63;
    const int wid  = t >> 6;
    const int r0 = blockIdx.x * 8;

    lcnt8[t] = *(const u64*)&cnts2[(size_t)t * N_NODES + r0];  // aligned
    const int4 s4 = ((const int4*)spillcnt)[lane];             // 256 ints
    const bool anyspill = __ballot((s4.x | s4.y | s4.z | s4.w) != 0) != 0ull;
    __syncthreads();

    for (int half = 0; half < 2; ++half) {
        const int d = wid * 2 + half;
        const int r = r0 + d;
        uint32* qp = &qbuf[d * QPAD2];

        // ---- prefix-compaction queue build (atomic-free, compare-free) ----
        int c0 = (int)((lcnt8[lane * 4 + 0] >> (8 * d)) & 0xFFu);
        int c1 = (int)((lcnt8[lane * 4 + 1] >> (8 * d)) & 0xFFu);
        int c2 = (int)((lcnt8[lane * 4 + 2] >> (8 * d)) & 0xFFu);
        int c3 = (int)((lcnt8[lane * 4 + 3] >> (8 * d)) & 0xFFu);
        int c = c0 + c1 + c2 + c3;
        int p = c;
        #pragma unroll
        for (int s = 1; s < 64; s <<= 1) {
            int v = __shfl_up(p, s);
            if (lane >= s) p += v;
        }
        int ntot = __shfl(p, 63);
        const uint32* strip = &bstore[(size_t)r * (NCHUNK * RCAP) + lane * (4 * RCAP)];
        int bo = p - c;
        #pragma unroll
        for (int j = 0; j < 4; ++j) {
            int cj = (j == 0) ? c0 : (j == 1) ? c1 : (j == 2) ? c2 : c3;
            const uint32* cell = strip + j * RCAP;
            uint4 v0 = {0, 0, 0, 0}, v1 = {0, 0, 0, 0};
            if (cj > 0) v0 = *(const uint4*)cell;         // 16B
            if (cj > 4) v1 = *(const uint4*)(cell + 4);   // rare
            if (cj > 0 && bo + 0 < CAP2) qp[bo + 0] = v0.x;
            if (cj > 1 && bo + 1 < CAP2) qp[bo + 1] = v0.y;
            if (cj > 2 && bo + 2 < CAP2) qp[bo + 2] = v0.z;
            if (cj > 3 && bo + 3 < CAP2) qp[bo + 3] = v0.w;
            if (cj > 4 && bo + 4 < CAP2) qp[bo + 4] = v1.x;
            if (cj > 5 && bo + 5 < CAP2) qp[bo + 5] = v1.y;
            if (cj > 6 && bo + 6 < CAP2) qp[bo + 6] = v1.z;
            if (cj > 7 && bo + 7 < CAP2) qp[bo + 7] = v1.w;
            bo += cj;
        }

        if (anyspill) {                                   // ~never taken
            for (int ch = 0; ch < NCHUNK; ++ch) {
                int sc = spillcnt[ch];
                for (int k = 0; k < sc; ++k) {
                    uint2 e = spill[(size_t)ch * SPILLCAP + k];
                    if (e.y == (uint32)r) {
                        if (lane == 0 && ntot < CAP2) qp[ntot] = e.x;
                        ntot++;
                    }
                }
            }
        }

        float a0 = 0.f, a1 = 0.f;
        if (ntot <= CAP2) {
            if (lane < 16) qp[ntot + lane] = 0;    // zero pad (val=+0.0 recs)
            __builtin_amdgcn_s_waitcnt(0);         // wave-local LDS drain

            const int npad = (ntot + 7) & ~7;
            uint32 rq0,rq1,rq2,rq3,rq4,rq5,rq6,rq7;
            uint32 hh0,hh1,hh2,hh3,hh4,hh5,hh6,hh7;
            rq0 = qp[0]; hh0 = h2[((rq0 & 0xFFFFu) << 6) + lane];
            rq1 = qp[1]; hh1 = h2[((rq1 & 0xFFFFu) << 6) + lane];
            rq2 = qp[2]; hh2 = h2[((rq2 & 0xFFFFu) << 6) + lane];
            rq3 = qp[3]; hh3 = h2[((rq3 & 0xFFFFu) << 6) + lane];
            rq4 = qp[4]; hh4 = h2[((rq4 & 0xFFFFu) << 6) + lane];
            rq5 = qp[5]; hh5 = h2[((rq5 & 0xFFFFu) << 6) + lane];
            rq6 = qp[6]; hh6 = h2[((rq6 & 0xFFFFu) << 6) + lane];
            rq7 = qp[7]; hh7 = h2[((rq7 & 0xFFFFu) << 6) + lane];

#define CONSUME_PREFETCH(RQ, HH, P)                                          \
    {                                                                        \
        a0 = fmaf(__uint_as_float(RQ & 0xFFFF0000u),                         \
                  __uint_as_float(HH << 16), a0);                            \
        a1 = fmaf(__uint_as_float(RQ & 0xFFFF0000u),                         \
                  __uint_as_float(HH & 0xFFFF0000u), a1);                    \
        uint32 rn = qp[j + 8 + P];                                           \
        RQ = rn; HH = h2[((rn & 0xFFFFu) << 6) + lane];                      \
    }

            for (int j = 0; j < npad; j += 8) {
                CONSUME_PREFETCH(rq0, hh0, 0)
                CONSUME_PREFETCH(rq1, hh1, 1)
                CONSUME_PREFETCH(rq2, hh2, 2)
                CONSUME_PREFETCH(rq3, hh3, 3)
                CONSUME_PREFETCH(rq4, hh4, 4)
                CONSUME_PREFETCH(rq5, hh5, 5)
                CONSUME_PREFETCH(rq6, hh6, 6)
                CONSUME_PREFETCH(rq7, hh7, 7)
            }
#undef CONSUME_PREFETCH
        } else {
            // slow path (row > CAP2 records; ~never): rescan row cells + spills.
            for (int ch = 0; ch < NCHUNK; ++ch) {
                int c2v = (int)((lcnt8[ch] >> (8 * d)) & 0xFFu);
                for (int k = 0; k < c2v; ++k) {
                    uint32 rec = bstore[(size_t)r * (NCHUNK * RCAP) + ch * RCAP + k];
                    uint32 hv = h2[((rec & 0xFFFFu) << 6) + lane];
                    a0 = fmaf(__uint_as_float(rec & 0xFFFF0000u),
                              __uint_as_float(hv << 16), a0);
                    a1 = fmaf(__uint_as_float(rec & 0xFFFF0000u),
                              __uint_as_float(hv & 0xFFFF0000u), a1);
                }
            }
            for (int ch = 0; ch < NCHUNK; ++ch) {
                int sc = spillcnt[ch];
                for (int k = 0; k < sc; ++k) {
                    uint2 e = spill[(size_t)ch * SPILLCAP + k];
                    if (e.y == (uint32)r) {
                        uint32 hv = h2[((e.x & 0xFFFFu) << 6) + lane];
                        a0 = fmaf(__uint_as_float(e.x & 0xFFFF0000u),
                                  __uint_as_float(hv << 16), a0);
                        a1 = fmaf(__uint_as_float(e.x & 0xFFFF0000u),
                                  __uint_as_float(hv & 0xFFFF0000u), a1);
                    }
                }
            }
        }

        out[(size_t)r * D + lane]      = a0 + bias[lane];
        out[(size_t)r * D + 64 + lane] = a1 + bias[lane + 64];
    }
}

extern "C" void kernel_launch(void* const* d_in, const int* in_sizes, int n_in,
                              void* d_out, int out_size, void* d_ws, size_t ws_size,
                              hipStream_t stream)
{
    const float* x    = (const float*)d_in[0];
    const float* aval = (const float*)d_in[1];
    const float* w    = (const float*)d_in[2];
    const float* bias = (const float*)d_in[3];
    const int* arow   = (const int*)d_in[4];
    const int* acol   = (const int*)d_in[5];

    char* ws = (char*)d_ws;
    uint32* h2       = (uint32*)(ws);              //  2,560,000 B
    u8*     cnts2    = (u8*)(ws + 2560000);        //  2,560,000 B (256 x 10000)
    int*    spillcnt = (int*)(ws + 5120000);       //      1,024 B (256)
    uint32* bstore   = (uint32*)(ws + 5121024);    // 81,920,000 B (10000x256x8x4)
    uint2*  spill    = (uint2*)(ws + 87041024);    //  5,120,000 B (256x2500x8)
    // total 92,161,024 B (ws ~= 256MB per the poison fill's WRITE_SIZE);
    // no memset: cnts2/spillcnt written unconditionally by k1.

    gemm_scatter_kernel<<<GRID1, 256, 0, stream>>>(
        x, w, arow, acol, aval, h2, cnts2, spillcnt, bstore, spill);
    spmm_kernel<<<N_NODES / 8, 256, 0, stream>>>(
        bstore, cnts2, spillcnt, spill, h2, bias, (float*)d_out);
}